// Round 15
// baseline (471.063 us; speedup 1.0000x reference)
//
#include <hip/hip_runtime.h>

#define B_DIM 8
#define S_LEN 4096
#define D_DIM 512
#define H_DIM 512

#define DECAY_F 0.90483743f   // exp(-0.1)
#define ALPHA_F 0.01f
#define EPS_F   1e-6f

#define KT 16
#define NCHUNK 256            // scan chunks of 16 steps
#define NSCAN_BLOCKS 32

// ================= GEMM tile body (R7/R11, proven 214us standalone) ==============
// 128x128 tile, KT=16, single-buffer LDS, register prefetch, 8x8 wave grid
// tr=lane>>3 / tc=lane&7, cols {c0,c0+32}. Accumulation order identical since R2
// -> bit-identical h.
__device__ __forceinline__ void gemm_tile(const float* __restrict__ x,
                                          const float* __restrict__ W,
                                          const float* __restrict__ bias,
                                          float* __restrict__ out,
                                          float (*As)[132], float (*Bs)[132],
                                          int bm, int bn) {
    const int tid = threadIdx.x;
    const int waveId = tid >> 6;
    const int waveR = waveId & 1;
    const int waveC = waveId >> 1;
    const int lane = tid & 63;
    const int tr = lane >> 3;
    const int tc = lane & 7;
    const int rbase = waveR * 64 + tr * 8;
    const int c0 = waveC * 64 + tc * 4;
    const int c1 = c0 + 32;

    const int lrow = tid >> 2;
    const int lk4  = (tid & 3) * 4;

    const float* xa = &x[(size_t)(bm + lrow) * D_DIM + lk4];
    const float* xb = &x[(size_t)(bm + lrow + 64) * D_DIM + lk4];
    const float* wa = &W[(size_t)(bn + lrow) * D_DIM + lk4];
    const float* wb = &W[(size_t)(bn + lrow + 64) * D_DIM + lk4];

    float acc[8][8];
#pragma unroll
    for (int i = 0; i < 8; ++i)
#pragma unroll
        for (int j = 0; j < 8; ++j) acc[i][j] = 0.f;

    float4 a0 = *reinterpret_cast<const float4*>(xa);
    float4 a1 = *reinterpret_cast<const float4*>(xb);
    float4 b0 = *reinterpret_cast<const float4*>(wa);
    float4 b1 = *reinterpret_cast<const float4*>(wb);

    for (int kk = 0; kk < D_DIM; kk += KT) {
        __syncthreads();
        As[lk4 + 0][lrow]      = a0.x;
        As[lk4 + 1][lrow]      = a0.y;
        As[lk4 + 2][lrow]      = a0.z;
        As[lk4 + 3][lrow]      = a0.w;
        As[lk4 + 0][lrow + 64] = a1.x;
        As[lk4 + 1][lrow + 64] = a1.y;
        As[lk4 + 2][lrow + 64] = a1.z;
        As[lk4 + 3][lrow + 64] = a1.w;
        Bs[lk4 + 0][lrow]      = b0.x;
        Bs[lk4 + 1][lrow]      = b0.y;
        Bs[lk4 + 2][lrow]      = b0.z;
        Bs[lk4 + 3][lrow]      = b0.w;
        Bs[lk4 + 0][lrow + 64] = b1.x;
        Bs[lk4 + 1][lrow + 64] = b1.y;
        Bs[lk4 + 2][lrow + 64] = b1.z;
        Bs[lk4 + 3][lrow + 64] = b1.w;
        __syncthreads();

        if (kk + KT < D_DIM) {
            a0 = *reinterpret_cast<const float4*>(xa + kk + KT);
            a1 = *reinterpret_cast<const float4*>(xb + kk + KT);
            b0 = *reinterpret_cast<const float4*>(wa + kk + KT);
            b1 = *reinterpret_cast<const float4*>(wb + kk + KT);
        }

#pragma unroll
        for (int k = 0; k < KT; ++k) {
            const float4 av0 = *reinterpret_cast<const float4*>(&As[k][rbase]);
            const float4 av1 = *reinterpret_cast<const float4*>(&As[k][rbase + 4]);
            const float4 bv0 = *reinterpret_cast<const float4*>(&Bs[k][c0]);
            const float4 bv1 = *reinterpret_cast<const float4*>(&Bs[k][c1]);
            const float am[8]  = {av0.x, av0.y, av0.z, av0.w, av1.x, av1.y, av1.z, av1.w};
            const float bn_[8] = {bv0.x, bv0.y, bv0.z, bv0.w, bv1.x, bv1.y, bv1.z, bv1.w};
#pragma unroll
            for (int i = 0; i < 8; ++i)
#pragma unroll
                for (int j = 0; j < 8; ++j) acc[i][j] += am[i] * bn_[j];
        }
    }

    const float4 bias0 = *reinterpret_cast<const float4*>(&bias[bn + c0]);
    const float4 bias1 = *reinterpret_cast<const float4*>(&bias[bn + c1]);
    const float bb[8] = {bias0.x, bias0.y, bias0.z, bias0.w, bias1.x, bias1.y, bias1.z, bias1.w};

#pragma unroll
    for (int i = 0; i < 8; ++i) {
        const size_t row = (size_t)(bm + rbase + i);
        float4 o0, o1;
        o0.x = acc[i][0] + bb[0]; o0.y = acc[i][1] + bb[1];
        o0.z = acc[i][2] + bb[2]; o0.w = acc[i][3] + bb[3];
        o1.x = acc[i][4] + bb[4]; o1.y = acc[i][5] + bb[5];
        o1.z = acc[i][6] + bb[6]; o1.w = acc[i][7] + bb[7];
        *reinterpret_cast<float4*>(&out[row * H_DIM + bn + c0]) = o0;
        *reinterpret_cast<float4*>(&out[row * H_DIM + bn + c1]) = o1;
    }
}

// ================= Scan: 2 independent chains per lane (ran in R13) ==============
// One wave handles chains h = hb+lane and hb+64+lane of batch b. Chunk = 16 steps;
// LDS [2][16][128] = 16KB via global_load_lds; counted vmcnt. Gates every 8 chunks
// poll flags[b*32+stn] == 4 (R10-R12 protocol). Per-chain statement sequence
// identical to the absmax-0.0 lineage; interleaving independent chains cannot
// change either chain's values.
__device__ __forceinline__ void scan_block(float* __restrict__ gio,  // out + b*S*H + hb
                                           float* sbuf, const int* flagrow, int lane,
                                           float* __restrict__ vout,
                                           float* __restrict__ thout, int chainA) {
#define SSTATE(sfx)                                                   \
    float v##sfx = 0.f;                                               \
    float theta##sfx = 1.f;                                           \
    float tden##sfx = theta##sfx + EPS_F;                             \
    float rs##sfx = __builtin_amdgcn_rcpf(tden##sfx);                 \
    float es##sfx = fmaf(-tden##sfx, rs##sfx, 1.0f);                  \
    float r1##sfx = fmaf(es##sfx, rs##sfx, rs##sfx);                  \
    float es2##sfx = fmaf(-tden##sfx, r1##sfx, 1.0f);                 \
    float r0##sfx = fmaf(es2##sfx, r1##sfx, r1##sfx);                 \
    float cl##sfx = 32.f * theta##sfx;
    SSTATE(A)
    SSTATE(B)
#undef SSTATE
    const float kSixteen = 16.0f;

#define STAGE16(DST, C)                                                              \
    do {                                                                             \
        const float* src_ = gio + (size_t)((C) * 16 + (lane >> 5)) * H_DIM           \
                              + ((lane & 31) << 2);                                  \
        _Pragma("unroll")                                                            \
        for (int i_ = 0; i_ < 8; ++i_) {                                             \
            __builtin_amdgcn_global_load_lds(                                        \
                (const __attribute__((address_space(1))) void*)(src_ + (size_t)(2 * i_) * H_DIM), \
                (__attribute__((address_space(3))) void*)((DST) + i_ * 256),         \
                16, 0, 0);                                                           \
        }                                                                            \
    } while (0)

    if (flagrow) {
        while (__hip_atomic_load(&flagrow[0], __ATOMIC_ACQUIRE, __HIP_MEMORY_SCOPE_AGENT) < 4)
            __builtin_amdgcn_s_sleep(1);
    }
    STAGE16(sbuf, 0);
    asm volatile("s_waitcnt vmcnt(0)" ::: "memory");

    for (int c = 0; c < NCHUNK; ++c) {
        if (c + 1 < NCHUNK) {
            if (((c + 1) & 7) == 0 && flagrow) {
                const int stn = (c + 1) >> 3;
                while (__hip_atomic_load(&flagrow[stn], __ATOMIC_ACQUIRE,
                                         __HIP_MEMORY_SCOPE_AGENT) < 4)
                    __builtin_amdgcn_s_sleep(1);
                asm volatile("s_waitcnt vmcnt(0)" ::: "memory");
                STAGE16(sbuf + ((c + 1) & 1) * 2048, c + 1);
            } else {
                STAGE16(sbuf + ((c + 1) & 1) * 2048, c + 1);
                // outstanding: stage(c)=8 (oldest), stores(c-1)=32, stage(c+1)=8
                asm volatile("s_waitcnt vmcnt(40)" ::: "memory");
            }
        } else {
            asm volatile("s_waitcnt vmcnt(32)" ::: "memory");
        }
        __builtin_amdgcn_sched_barrier(0);

        const float* sb = sbuf + (c & 1) * 2048 + lane;
        float rrA[16], rrB[16];
#pragma unroll
        for (int i = 0; i < 16; ++i) { rrA[i] = sb[i * 128]; rrB[i] = sb[i * 128 + 64]; }
        __builtin_amdgcn_sched_barrier(0);

        float* goutA = gio + (size_t)c * 16 * H_DIM + lane;

#define STEP(sfx, IT, OUT_EXPR)                                       \
        do {                                                          \
            float vv = v##sfx * DECAY_F + (IT);                       \
            asm("v_med3_f32 %0, %0, -%1, %1" : "+v"(vv) : "v"(cl##sfx)); \
            v##sfx = vv;                                              \
            const float q0 = v##sfx * r0##sfx;                        \
            const float e1 = fmaf(-tden##sfx, q0, v##sfx);            \
            const float nv = fmaf(e1, r0##sfx, q0);                   \
            float spike = floorf(nv);                                 \
            asm("v_med3_f32 %0, %0, 0, %1" : "+v"(spike) : "v"(kSixteen)); \
            v##sfx = v##sfx - spike * theta##sfx;                     \
            theta##sfx = theta##sfx + ALPHA_F * spike - ALPHA_F * (theta##sfx - 1.0f); \
            tden##sfx = theta##sfx + EPS_F;                           \
            const float rrcp = __builtin_amdgcn_rcpf(tden##sfx);      \
            const float ee = fmaf(-tden##sfx, rrcp, 1.0f);            \
            const float ra = fmaf(ee, rrcp, rrcp);                    \
            const float ee2 = fmaf(-tden##sfx, ra, 1.0f);             \
            r0##sfx = fmaf(ee2, ra, ra);                              \
            cl##sfx = 32.f * theta##sfx;                              \
            (OUT_EXPR) = spike;                                       \
        } while (0)

#pragma unroll
        for (int u = 0; u < 16; ++u) {
            STEP(A, rrA[u], goutA[(size_t)u * H_DIM]);
            STEP(B, rrB[u], goutA[(size_t)u * H_DIM + 64]);
        }
#undef STEP
        __builtin_amdgcn_sched_barrier(0);
    }

    vout[chainA]        = vA;
    thout[chainA]       = thetaA;
    vout[chainA + 64]   = vB;
    thout[chainA + 64]  = thetaB;
#undef STAGE16
}

// ================= fused kernel (R11 structure, proven 334us) ====================
// blocks 0..31: scan, ONE active wave each (threads 64..255 exit), 16KB dbuf,
//   s_setprio(1), 2 chains/lane.
// blocks 32..1055: GEMM 128x128 tiles, flat grid, s-tile-major (st = g>>5) so
//   completion order matches scan consumption order.
// Sync: flags[bb*32+st] count to 4 (nt=0..3); GEMM: __syncthreads (stores drained)
// + tid-0 RELEASE fetch_add; scan: ACQUIRE poll ==4. Protocol proven R10-R12.
__global__ __launch_bounds__(256) void fused_kernel(const float* __restrict__ x,
                                                    const float* __restrict__ W,
                                                    const float* __restrict__ bias,
                                                    float* __restrict__ out,
                                                    float* __restrict__ vout,
                                                    float* __restrict__ thout,
                                                    int* __restrict__ flags) {
    __shared__ __align__(16) char smem_raw[16896];
    const int bid = blockIdx.x;

    if (bid >= NSCAN_BLOCKS) {
        float (*As)[132] = reinterpret_cast<float (*)[132]>(smem_raw);
        float (*Bs)[132] = reinterpret_cast<float (*)[132]>(smem_raw + sizeof(float) * KT * 132);

        const int g  = bid - NSCAN_BLOCKS;   // 0..1023
        const int st = g >> 5;               // s-tile 0..31 (outer)
        const int bb = (g >> 2) & 7;         // batch
        const int nt = g & 3;                // n-tile
        const int bm = bb * S_LEN + st * 128;
        const int bn = nt * 128;

        gemm_tile(x, W, bias, out, As, Bs, bm, bn);

        __syncthreads();   // all waves' stores retired before the release add
        if (threadIdx.x == 0) {
            __hip_atomic_fetch_add(&flags[bb * 32 + st], 1,
                                   __ATOMIC_RELEASE, __HIP_MEMORY_SCOPE_AGENT);
        }
        return;
    }

    // scan role: one active wave per block
    if (threadIdx.x >= 64) return;
    __builtin_amdgcn_s_setprio(1);

    const int lane = threadIdx.x;
    const int b  = bid >> 2;             // 0..7
    const int hb = (bid & 3) << 7;       // 0,128,256,384

    float* sbuf = reinterpret_cast<float*>(smem_raw);
    float* gio = out + (size_t)b * S_LEN * H_DIM + hb;
    const int chainA = b * H_DIM + hb + lane;

    scan_block(gio, sbuf, flags + b * 32, lane, vout, thout, chainA);
}

// ================= fallback serial kernels (ws too small) ========================

__global__ __launch_bounds__(256) void gemm_kernel(const float* __restrict__ x,
                                                   const float* __restrict__ W,
                                                   const float* __restrict__ bias,
                                                   float* __restrict__ out) {
    __shared__ float As[KT][132];
    __shared__ float Bs[KT][132];
    const int bm = blockIdx.y * 128;
    const int bn = blockIdx.x * 128;
    gemm_tile(x, W, bias, out, As, Bs, bm, bn);
}

__global__ __launch_bounds__(64, 1) void scan_serial_kernel(float* __restrict__ io,
                                                            float* __restrict__ vout,
                                                            float* __restrict__ thout) {
    __shared__ __align__(16) float sbuf[4096];
    const int bid = blockIdx.x;
    const int lane = threadIdx.x;
    const int b  = bid >> 2;
    const int hb = (bid & 3) << 7;
    float* gio = io + (size_t)b * S_LEN * H_DIM + hb;
    const int chainA = b * H_DIM + hb + lane;
    scan_block(gio, sbuf, nullptr, lane, vout, thout, chainA);
}

extern "C" void kernel_launch(void* const* d_in, const int* in_sizes, int n_in,
                              void* d_out, int out_size, void* d_ws, size_t ws_size,
                              hipStream_t stream) {
    const float* x    = (const float*)d_in[0];
    const float* W    = (const float*)d_in[1];
    const float* bias = (const float*)d_in[2];

    float* out   = (float*)d_out;
    float* vout  = out + (size_t)B_DIM * S_LEN * H_DIM;
    float* thout = vout + B_DIM * H_DIM;

    if (ws_size >= 1024) {
        int* flags = (int*)d_ws;
        hipMemsetAsync(flags, 0, 1024, stream);
        fused_kernel<<<NSCAN_BLOCKS + 1024, 256, 0, stream>>>(x, W, bias, out,
                                                              vout, thout, flags);
    } else {
        dim3 grid(H_DIM / 128, (B_DIM * S_LEN) / 128);
        gemm_kernel<<<grid, 256, 0, stream>>>(x, W, bias, out);
        scan_serial_kernel<<<NSCAN_BLOCKS, 64, 0, stream>>>(out, vout, thout);
    }
}

// Round 16
// 444.587 us; speedup vs baseline: 1.0596x; 1.0596x over previous
//
#include <hip/hip_runtime.h>

#define B_DIM 8
#define S_LEN 4096
#define D_DIM 512
#define H_DIM 512

#define DECAY_F 0.90483743f   // exp(-0.1)
#define ALPHA_F 0.01f
#define EPS_F   1e-6f

#define KT 16
#define NSCAN_BLOCKS 64
#define NGEMM_BLOCKS 512      // 128 m-tiles(256) x 4 n-tiles(128), st-pair-major

// ================= GEMM tile body: 256x128 tile, 16x8 acc/thread ================
// Derived from R7/R11 (proven): same wave col mapping (c0, c0+32 -> dense 128B
// store segments), same k-ascending fma per element -> bit-identical h.
// M-tile doubled to cut LDS-read/FMA ratio from 4 b128/64 FMA to 6/128 (x0.75).
__device__ __forceinline__ void gemm_tile(const float* __restrict__ x,
                                          const float* __restrict__ W,
                                          const float* __restrict__ bias,
                                          float* __restrict__ out,
                                          float (*As)[260], float (*Bs)[132],
                                          int bm, int bn) {
    const int tid = threadIdx.x;
    const int waveId = tid >> 6;
    const int waveR = waveId & 1;        // 2 m-halves of 128 rows
    const int waveC = waveId >> 1;       // 2 n-halves of 64 cols
    const int lane = tid & 63;
    const int tr = lane >> 3;            // 0..7
    const int tc = lane & 7;             // 0..7 (col fast)
    const int rbase = waveR * 128 + tr * 16;   // 16 rows per thread
    const int c0 = waveC * 64 + tc * 4;
    const int c1 = c0 + 32;

    const int lrow = tid >> 2;          // 0..63
    const int lk4  = (tid & 3) * 4;     // 0,4,8,12

    const float* xr[4];
#pragma unroll
    for (int q = 0; q < 4; ++q)
        xr[q] = &x[(size_t)(bm + lrow + 64 * q) * D_DIM + lk4];
    const float* wa = &W[(size_t)(bn + lrow) * D_DIM + lk4];
    const float* wb = &W[(size_t)(bn + lrow + 64) * D_DIM + lk4];

    float acc[16][8];
#pragma unroll
    for (int i = 0; i < 16; ++i)
#pragma unroll
        for (int j = 0; j < 8; ++j) acc[i][j] = 0.f;

    // prologue: stage tile kk=0 into registers
    float4 ar[4];
#pragma unroll
    for (int q = 0; q < 4; ++q) ar[q] = *reinterpret_cast<const float4*>(xr[q]);
    float4 b0 = *reinterpret_cast<const float4*>(wa);
    float4 b1 = *reinterpret_cast<const float4*>(wb);

    for (int kk = 0; kk < D_DIM; kk += KT) {
        __syncthreads();
#pragma unroll
        for (int q = 0; q < 4; ++q) {
            As[lk4 + 0][lrow + 64 * q] = ar[q].x;
            As[lk4 + 1][lrow + 64 * q] = ar[q].y;
            As[lk4 + 2][lrow + 64 * q] = ar[q].z;
            As[lk4 + 3][lrow + 64 * q] = ar[q].w;
        }
        Bs[lk4 + 0][lrow]      = b0.x;
        Bs[lk4 + 1][lrow]      = b0.y;
        Bs[lk4 + 2][lrow]      = b0.z;
        Bs[lk4 + 3][lrow]      = b0.w;
        Bs[lk4 + 0][lrow + 64] = b1.x;
        Bs[lk4 + 1][lrow + 64] = b1.y;
        Bs[lk4 + 2][lrow + 64] = b1.z;
        Bs[lk4 + 3][lrow + 64] = b1.w;
        __syncthreads();

        // issue next tile's loads; latency hides under the FMA loop below
        if (kk + KT < D_DIM) {
#pragma unroll
            for (int q = 0; q < 4; ++q)
                ar[q] = *reinterpret_cast<const float4*>(xr[q] + kk + KT);
            b0 = *reinterpret_cast<const float4*>(wa + kk + KT);
            b1 = *reinterpret_cast<const float4*>(wb + kk + KT);
        }

#pragma unroll
        for (int k = 0; k < KT; ++k) {
            const float4 av0 = *reinterpret_cast<const float4*>(&As[k][rbase]);
            const float4 av1 = *reinterpret_cast<const float4*>(&As[k][rbase + 4]);
            const float4 av2 = *reinterpret_cast<const float4*>(&As[k][rbase + 8]);
            const float4 av3 = *reinterpret_cast<const float4*>(&As[k][rbase + 12]);
            const float4 bv0 = *reinterpret_cast<const float4*>(&Bs[k][c0]);
            const float4 bv1 = *reinterpret_cast<const float4*>(&Bs[k][c1]);
            const float am[16] = {av0.x, av0.y, av0.z, av0.w, av1.x, av1.y, av1.z, av1.w,
                                  av2.x, av2.y, av2.z, av2.w, av3.x, av3.y, av3.z, av3.w};
            const float bn_[8] = {bv0.x, bv0.y, bv0.z, bv0.w, bv1.x, bv1.y, bv1.z, bv1.w};
#pragma unroll
            for (int i = 0; i < 16; ++i)
#pragma unroll
                for (int j = 0; j < 8; ++j) acc[i][j] += am[i] * bn_[j];
        }
    }

    const float4 bias0 = *reinterpret_cast<const float4*>(&bias[bn + c0]);
    const float4 bias1 = *reinterpret_cast<const float4*>(&bias[bn + c1]);
    const float bb[8] = {bias0.x, bias0.y, bias0.z, bias0.w, bias1.x, bias1.y, bias1.z, bias1.w};

#pragma unroll
    for (int i = 0; i < 16; ++i) {
        const size_t row = (size_t)(bm + rbase + i);
        float4 o0, o1;
        o0.x = acc[i][0] + bb[0]; o0.y = acc[i][1] + bb[1];
        o0.z = acc[i][2] + bb[2]; o0.w = acc[i][3] + bb[3];
        o1.x = acc[i][4] + bb[4]; o1.y = acc[i][5] + bb[5];
        o1.z = acc[i][6] + bb[6]; o1.w = acc[i][7] + bb[7];
        *reinterpret_cast<float4*>(&out[row * H_DIM + bn + c0]) = o0;
        *reinterpret_cast<float4*>(&out[row * H_DIM + bn + c1]) = o1;
    }
}

// ================= Scan (R11 exact: 64 blocks, 1 chain/lane, proven) =============
__device__ __forceinline__ void stage_chunk(const float* __restrict__ gio, float* dstbase,
                                            int c, int lane) {
    const float* src = gio + (size_t)(c * 32 + (lane >> 4)) * H_DIM + ((lane & 15) << 2);
#pragma unroll
    for (int i = 0; i < 8; ++i) {
        __builtin_amdgcn_global_load_lds(
            (const __attribute__((address_space(1))) void*)(src + (size_t)i * 4 * H_DIM),
            (__attribute__((address_space(3))) void*)(dstbase + i * 256),
            16, 0, 0);
    }
}

__device__ __forceinline__ void scan_wave(float* __restrict__ gio, float* sbuf,
                                          const int* flagrow, int lane,
                                          float* __restrict__ vout,
                                          float* __restrict__ thout, int chain) {
    float v = 0.f;
    float theta = 1.f;
    float tden = theta + EPS_F;
    float rs = __builtin_amdgcn_rcpf(tden);
    float es = fmaf(-tden, rs, 1.0f);
    float r1 = fmaf(es, rs, rs);
    float es2 = fmaf(-tden, r1, 1.0f);
    float r0 = fmaf(es2, r1, r1);
    float cl = 32.f * theta;
    const float kSixteen = 16.0f;

    if (flagrow) {
        while (__hip_atomic_load(&flagrow[0], __ATOMIC_ACQUIRE, __HIP_MEMORY_SCOPE_AGENT) < 4)
            __builtin_amdgcn_s_sleep(1);
    }
    stage_chunk(gio, sbuf, 0, lane);
    asm volatile("s_waitcnt vmcnt(0)" ::: "memory");

    const int NC = S_LEN / 32;   // 128
    for (int c = 0; c < NC; ++c) {
        if (c + 1 < NC) {
            if (((c + 1) & 3) == 0 && flagrow) {
                const int stn = (c + 1) >> 2;
                while (__hip_atomic_load(&flagrow[stn], __ATOMIC_ACQUIRE,
                                         __HIP_MEMORY_SCOPE_AGENT) < 4)
                    __builtin_amdgcn_s_sleep(1);
                asm volatile("s_waitcnt vmcnt(0)" ::: "memory");
                stage_chunk(gio, sbuf + ((c + 1) & 1) * 2048, c + 1, lane);
            } else {
                stage_chunk(gio, sbuf + ((c + 1) & 1) * 2048, c + 1, lane);
                // outstanding: stage(c)=8, stores(c-1)=32, stage(c+1)=8 -> retire oldest 8
                asm volatile("s_waitcnt vmcnt(40)" ::: "memory");
            }
        } else {
            asm volatile("s_waitcnt vmcnt(32)" ::: "memory");
        }
        __builtin_amdgcn_sched_barrier(0);

        const float* sb = sbuf + (c & 1) * 2048 + lane;
        float rr[32];
#pragma unroll
        for (int i = 0; i < 32; ++i) rr[i] = sb[i * 64];
        __builtin_amdgcn_sched_barrier(0);

        float* gout = gio + (size_t)c * 32 * H_DIM + lane;

#pragma unroll
        for (int u = 0; u < 32; ++u) {
            float vv = v * DECAY_F + rr[u];
            asm("v_med3_f32 %0, %0, -%1, %1" : "+v"(vv) : "v"(cl));
            v = vv;

            const float q0 = v * r0;
            const float e1 = fmaf(-tden, q0, v);
            const float nv = fmaf(e1, r0, q0);

            float spike = floorf(nv);
            asm("v_med3_f32 %0, %0, 0, %1" : "+v"(spike) : "v"(kSixteen));

            v = v - spike * theta;
            theta = theta + ALPHA_F * spike - ALPHA_F * (theta - 1.0f);

            tden = theta + EPS_F;
            const float rrcp = __builtin_amdgcn_rcpf(tden);
            const float ee = fmaf(-tden, rrcp, 1.0f);
            const float ra = fmaf(ee, rrcp, rrcp);
            const float ee2 = fmaf(-tden, ra, 1.0f);
            r0 = fmaf(ee2, ra, ra);
            cl = 32.f * theta;

            gout[(size_t)u * H_DIM] = spike;
        }
        __builtin_amdgcn_sched_barrier(0);
    }

    vout[chain]  = v;
    thout[chain] = theta;
}

// ================= fused kernel (R11 structure; GEMM tiles now 256x128) ==========
// blocks 0..63: scan, ONE active wave each (threads 64..255 exit), 16KB dbuf,
//   s_setprio(1), 1 chain/lane (R11-proven; R15's 2-chain regressed).
// blocks 64..575: GEMM 256x128 tiles, flat grid, st-pair-major:
//   g = stp*32 + bb*4 + nt; bm = bb*4096 + stp*256. Each tile completion releases
//   BOTH s-tiles it covers (flags[bb*32+2*stp] and +1), each counting to 4 (nt).
// Sync protocol unchanged (proven R10-R12): __syncthreads drains stores, tid-0
// RELEASE fetch_add; scan ACQUIRE-polls ==4.
__global__ __launch_bounds__(256) void fused_kernel(const float* __restrict__ x,
                                                    const float* __restrict__ W,
                                                    const float* __restrict__ bias,
                                                    float* __restrict__ out,
                                                    float* __restrict__ vout,
                                                    float* __restrict__ thout,
                                                    int* __restrict__ flags) {
    __shared__ __align__(16) char smem_raw[sizeof(float) * KT * 260 + sizeof(float) * KT * 132];
    const int bid = blockIdx.x;

    if (bid >= NSCAN_BLOCKS) {
        float (*As)[260] = reinterpret_cast<float (*)[260]>(smem_raw);
        float (*Bs)[132] = reinterpret_cast<float (*)[132]>(smem_raw + sizeof(float) * KT * 260);

        const int g   = bid - NSCAN_BLOCKS;  // 0..511
        const int stp = g >> 5;              // st-pair 0..15 (outer -> s-order)
        const int bb  = (g >> 2) & 7;        // batch
        const int nt  = g & 3;               // n-tile
        const int bm = bb * S_LEN + stp * 256;
        const int bn = nt * 128;

        gemm_tile(x, W, bias, out, As, Bs, bm, bn);

        __syncthreads();   // all waves' stores retired before the release adds
        if (threadIdx.x == 0) {
            __hip_atomic_fetch_add(&flags[bb * 32 + 2 * stp], 1,
                                   __ATOMIC_RELEASE, __HIP_MEMORY_SCOPE_AGENT);
            __hip_atomic_fetch_add(&flags[bb * 32 + 2 * stp + 1], 1,
                                   __ATOMIC_RELEASE, __HIP_MEMORY_SCOPE_AGENT);
        }
        return;
    }

    // scan role: one active wave per block
    if (threadIdx.x >= 64) return;
    __builtin_amdgcn_s_setprio(1);

    const int lane = threadIdx.x;
    const int b  = bid >> 3;             // 0..7
    const int h0 = (bid & 7) << 6;       // 0,64,...,448

    float* sbuf = reinterpret_cast<float*>(smem_raw);
    float* gio = out + (size_t)b * S_LEN * H_DIM + h0;
    const int chain = b * H_DIM + h0 + lane;

    scan_wave(gio, sbuf, flags + b * 32, lane, vout, thout, chain);
}

// ================= fallback serial kernels (ws too small) ========================

__global__ __launch_bounds__(256) void gemm_kernel(const float* __restrict__ x,
                                                   const float* __restrict__ W,
                                                   const float* __restrict__ bias,
                                                   float* __restrict__ out) {
    __shared__ float As[KT][260];
    __shared__ float Bs[KT][132];
    const int bm = blockIdx.y * 256;
    const int bn = blockIdx.x * 128;
    gemm_tile(x, W, bias, out, As, Bs, bm, bn);
}

__global__ __launch_bounds__(64, 1) void scan_serial_kernel(float* __restrict__ io,
                                                            float* __restrict__ vout,
                                                            float* __restrict__ thout) {
    __shared__ __align__(16) float sbuf[4096];
    const int bid = blockIdx.x;
    const int lane = threadIdx.x;
    const int b  = bid >> 3;
    const int h0 = (bid & 7) << 6;
    float* gio = io + (size_t)b * S_LEN * H_DIM + h0;
    const int chain = b * H_DIM + h0 + lane;
    scan_wave(gio, sbuf, nullptr, lane, vout, thout, chain);
}

extern "C" void kernel_launch(void* const* d_in, const int* in_sizes, int n_in,
                              void* d_out, int out_size, void* d_ws, size_t ws_size,
                              hipStream_t stream) {
    const float* x    = (const float*)d_in[0];
    const float* W    = (const float*)d_in[1];
    const float* bias = (const float*)d_in[2];

    float* out   = (float*)d_out;
    float* vout  = out + (size_t)B_DIM * S_LEN * H_DIM;
    float* thout = vout + B_DIM * H_DIM;

    if (ws_size >= 1024) {
        int* flags = (int*)d_ws;
        hipMemsetAsync(flags, 0, 1024, stream);
        fused_kernel<<<NSCAN_BLOCKS + NGEMM_BLOCKS, 256, 0, stream>>>(x, W, bias, out,
                                                                      vout, thout, flags);
    } else {
        dim3 grid(H_DIM / 128, (B_DIM * S_LEN) / 256);
        gemm_kernel<<<grid, 256, 0, stream>>>(x, W, bias, out);
        scan_serial_kernel<<<NSCAN_BLOCKS, 64, 0, stream>>>(out, vout, thout);
    }
}